// Round 1
// baseline (2292.812 us; speedup 1.0000x reference)
//
#include <hip/hip_runtime.h>
#include <math.h>

#define NN 32
#define EE 512
#define TT 512
#define MM (NN*TT)      // 16384 rows
#define NE 8192         // codes

#define ROWS 64         // rows per block
#define JTs 256         // j-tile
#define KCs 32          // k-chunk
#define THR 512         // threads per block

// ---------------- znorm: numpy-pairwise sum of squares per row (stride T) ----
__global__ void k_znorm(const float* __restrict__ z, float* __restrict__ znorm) {
    int m = blockIdx.x * 256 + threadIdx.x;           // 0..16383
    int n = m >> 9;
    int t = m & 511;
    const float* base = z + (size_t)n * EE * TT + t;  // element e at base[e*TT]
    float h[4];
    for (int hh = 0; hh < 4; ++hh) {
        const float* p = base + (size_t)(hh * 128) * TT;
        float r[8];
#pragma unroll
        for (int q = 0; q < 8; ++q) { float v = p[(size_t)q * TT]; r[q] = __fmul_rn(v, v); }
        for (int i = 8; i < 128; i += 8) {
#pragma unroll
            for (int q = 0; q < 8; ++q) {
                float v = p[(size_t)(i + q) * TT];
                r[q] = __fadd_rn(r[q], __fmul_rn(v, v));
            }
        }
        h[hh] = __fadd_rn(__fadd_rn(__fadd_rn(r[0], r[1]), __fadd_rn(r[2], r[3])),
                          __fadd_rn(__fadd_rn(r[4], r[5]), __fadd_rn(r[6], r[7])));
    }
    znorm[m] = __fadd_rn(__fadd_rn(h[0], h[1]), __fadd_rn(h[2], h[3]));
}

// ---------------- enorm: per-code sum of squares (contiguous) ----------------
__global__ void k_enorm(const float* __restrict__ emb, float* __restrict__ enorm) {
    int j = blockIdx.x * 256 + threadIdx.x;           // 0..8191
    const float* base = emb + (size_t)j * EE;
    float h[4];
    for (int hh = 0; hh < 4; ++hh) {
        const float* p = base + hh * 128;
        float r[8];
#pragma unroll
        for (int q = 0; q < 8; ++q) { float v = p[q]; r[q] = __fmul_rn(v, v); }
        for (int i = 8; i < 128; i += 8) {
#pragma unroll
            for (int q = 0; q < 8; ++q) {
                float v = p[i + q];
                r[q] = __fadd_rn(r[q], __fmul_rn(v, v));
            }
        }
        h[hh] = __fadd_rn(__fadd_rn(__fadd_rn(r[0], r[1]), __fadd_rn(r[2], r[3])),
                          __fadd_rn(__fadd_rn(r[4], r[5]), __fadd_rn(r[6], r[7])));
    }
    enorm[j] = __fadd_rn(__fadd_rn(h[0], h[1]), __fadd_rn(h[2], h[3]));
}

// ---------------- main: fused distance GEMM + argmin + z_q + loss ------------
__global__ __launch_bounds__(THR) void k_main(
    const float* __restrict__ z, const float* __restrict__ emb,
    const float* __restrict__ znorm, const float* __restrict__ enorm,
    float* __restrict__ out_zq, int* __restrict__ counts,
    float* __restrict__ loss_part)
{
    __shared__ float et[KCs][JTs + 4];   // emb tile, k-major, stride 260 (16B aligned)
    __shared__ float zt[KCs][ROWS];      // z tile, k-major
    __shared__ int   bj[ROWS];
    __shared__ float lred[8];

    const int tid = threadIdx.x;
    const int blk = blockIdx.x;          // 0..255
    const int n   = blk >> 3;
    const int t0  = (blk & 7) * 64;
    const size_t zbase = (size_t)n * EE * TT + t0;

    const int tj = tid & 31;             // j-group: columns {4tj..+3} U {128+4tj..+3}
    const int tr = tid >> 5;             // row-group: rows 4tr..4tr+3

    float zn[4];
#pragma unroll
    for (int r = 0; r < 4; ++r) zn[r] = znorm[blk * ROWS + 4 * tr + r];

    float best_d[4];
    int   best_j[4];
#pragma unroll
    for (int r = 0; r < 4; ++r) { best_d[r] = 3.4028235e38f; best_j[r] = 0; }

    for (int jt = 0; jt < NE / JTs; ++jt) {
        const int jb = jt * JTs;
        float acc[4][8];
#pragma unroll
        for (int r = 0; r < 4; ++r)
#pragma unroll
            for (int c = 0; c < 8; ++c) acc[r][c] = 0.f;

        for (int kc = 0; kc < EE / KCs; ++kc) {
            __syncthreads();
            // stage emb tile transposed: et[k][j] <- emb[jb+j][kc*32+k]
#pragma unroll
            for (int rep = 0; rep < 4; ++rep) {
                int idx = rep * THR + tid;
                int j   = idx >> 3;
                int k4  = idx & 7;
                float4 v = *(const float4*)&emb[(size_t)(jb + j) * EE + kc * KCs + 4 * k4];
                et[4 * k4 + 0][j] = v.x;
                et[4 * k4 + 1][j] = v.y;
                et[4 * k4 + 2][j] = v.z;
                et[4 * k4 + 3][j] = v.w;
            }
            // stage z tile: zt[k][t] <- z[n][kc*32+k][t0+t]  (coalesced, conflict-free)
            {
                int kk = tid >> 4;
                int f4 = tid & 15;
                float4 v = *(const float4*)&z[zbase + (size_t)(kc * KCs + kk) * TT + 4 * f4];
                *(float4*)&zt[kk][4 * f4] = v;
            }
            __syncthreads();
#pragma unroll 8
            for (int kk = 0; kk < KCs; ++kk) {
                float4 zv = *(const float4*)&zt[kk][4 * tr];
                float4 e0 = *(const float4*)&et[kk][4 * tj];
                float4 e1 = *(const float4*)&et[kk][128 + 4 * tj];
                float za[4] = { zv.x, zv.y, zv.z, zv.w };
                float eb[8] = { e0.x, e0.y, e0.z, e0.w, e1.x, e1.y, e1.z, e1.w };
#pragma unroll
                for (int r = 0; r < 4; ++r)
#pragma unroll
                    for (int c = 0; c < 8; ++c)
                        acc[r][c] = fmaf(za[r], eb[c], acc[r][c]);
            }
        }
        // fold distances into running argmin (numpy rounding: (zn+en) - 2*dot)
#pragma unroll
        for (int c = 0; c < 8; ++c) {
            const int jl = (c < 4) ? (4 * tj + c) : (128 + 4 * tj + (c - 4));
            const float en = enorm[jb + jl];
#pragma unroll
            for (int r = 0; r < 4; ++r) {
                float d = fmaf(-2.0f, acc[r][c], __fadd_rn(zn[r], en));
                if (d < best_d[r]) { best_d[r] = d; best_j[r] = jb + jl; }
            }
        }
    }

    // ---- block-wide argmin per row (tie -> smaller j), alias et as scratch ----
    __syncthreads();
    float* rd = &et[0][0];               // [ROWS][32] floats
    int*   rj = (int*)(rd + ROWS * 32);  // [ROWS][32] ints
#pragma unroll
    for (int r = 0; r < 4; ++r) {
        rd[(4 * tr + r) * 32 + tj] = best_d[r];
        rj[(4 * tr + r) * 32 + tj] = best_j[r];
    }
    __syncthreads();
    if (tid < ROWS) {
        float bd = rd[tid * 32];
        int   b  = rj[tid * 32];
        for (int c = 1; c < 32; ++c) {
            float dd = rd[tid * 32 + c];
            int   jj = rj[tid * 32 + c];
            if (dd < bd || (dd == bd && jj < b)) { bd = dd; b = jj; }
        }
        bj[tid] = b;
        atomicAdd(&counts[b], 1);
    }
    __syncthreads();

    // ---- z_q straight-through write (coalesced along t) + loss partial ----
    float lacc = 0.f;
    for (int i = tid; i < ROWS * EE; i += THR) {
        int e  = i >> 6;
        int rr = i & 63;
        int j  = bj[rr];
        float q  = emb[(size_t)j * EE + e];
        size_t zi = zbase + (size_t)e * TT + rr;
        float zf = z[zi];
        float diff = __fsub_rn(q, zf);
        out_zq[zi] = __fadd_rn(zf, diff);   // zf + (z_q - zf), numpy ST rounding
        lacc = fmaf(diff, diff, lacc);
    }
#pragma unroll
    for (int off = 32; off; off >>= 1) lacc += __shfl_down(lacc, off);
    if ((tid & 63) == 0) lred[tid >> 6] = lacc;
    __syncthreads();
    if (tid == 0) {
        float s = ((lred[0] + lred[1]) + (lred[2] + lred[3]))
                + ((lred[4] + lred[5]) + (lred[6] + lred[7]));
        loss_part[blk] = s;
    }
}

// ---------------- final scalars: loss + perplexity ---------------------------
__global__ void k_final(const int* __restrict__ counts,
                        const float* __restrict__ loss_part,
                        float* __restrict__ out)
{
    __shared__ float lw[4], pw[4];
    int tid = threadIdx.x;
    float l = loss_part[tid];            // 256 partials, 256 threads
#pragma unroll
    for (int off = 32; off; off >>= 1) l += __shfl_down(l, off);
    if ((tid & 63) == 0) lw[tid >> 6] = l;
    float p = 0.f;
    for (int j = tid; j < NE; j += 256) {
        float e = (float)counts[j] * (1.0f / (float)MM);
        p += e * logf(e + 1e-10f);
    }
#pragma unroll
    for (int off = 32; off; off >>= 1) p += __shfl_down(p, off);
    if ((tid & 63) == 0) pw[tid >> 6] = p;
    __syncthreads();
    if (tid == 0) {
        float ls = (lw[0] + lw[1]) + (lw[2] + lw[3]);
        float m  = ls / (float)((size_t)MM * EE);
        out[(size_t)MM * EE] = m + 0.25f * m;           // mean + BETA*mean
        float ps = (pw[0] + pw[1]) + (pw[2] + pw[3]);
        out[(size_t)MM * EE + 1] = expf(-ps);
    }
}

extern "C" void kernel_launch(void* const* d_in, const int* in_sizes, int n_in,
                              void* d_out, int out_size, void* d_ws, size_t ws_size,
                              hipStream_t stream) {
    const float* z   = (const float*)d_in[0];
    const float* emb = (const float*)d_in[1];
    float* out = (float*)d_out;

    float* znorm  = (float*)d_ws;            // 16384 f32
    float* enorm  = znorm + MM;              // 8192 f32
    int*   counts = (int*)(enorm + NE);      // 8192 i32
    float* parts  = (float*)(counts + NE);   // 256 f32

    k_znorm<<<MM / 256, 256, 0, stream>>>(z, znorm);
    k_enorm<<<NE / 256, 256, 0, stream>>>(emb, enorm);
    hipMemsetAsync(counts, 0, NE * sizeof(int), stream);
    k_main<<<MM / ROWS, THR, 0, stream>>>(z, emb, znorm, enorm, out, counts, parts);
    k_final<<<1, 256, 0, stream>>>(counts, parts, out);
}

// Round 2
// 625.576 us; speedup vs baseline: 3.6651x; 3.6651x over previous
//
#include <hip/hip_runtime.h>
#include <math.h>

#define NN 32
#define EE 512
#define TT 512
#define MM (NN*TT)      // 16384 rows
#define NE 8192         // codes

typedef __attribute__((ext_vector_type(8))) short bfrag8;
typedef __attribute__((ext_vector_type(16))) float facc16;

// RTNE fp32 -> bf16, also returning the bf16 value re-expanded to fp32
__device__ __forceinline__ ushort bf16_rtne(float v, float* as_f) {
    unsigned u = __float_as_uint(v);
    unsigned r = u + 0x7FFFu + ((u >> 16) & 1u);
    *as_f = __uint_as_float(r & 0xFFFF0000u);
    return (ushort)(r >> 16);
}

// ---------------- znorm: numpy-pairwise sum of squares per row (stride T) ----
__global__ void k_znorm(const float* __restrict__ z, float* __restrict__ znorm) {
    int m = blockIdx.x * 256 + threadIdx.x;
    int n = m >> 9;
    int t = m & 511;
    const float* base = z + (size_t)n * EE * TT + t;
    float h[4];
    for (int hh = 0; hh < 4; ++hh) {
        const float* p = base + (size_t)(hh * 128) * TT;
        float r[8];
#pragma unroll
        for (int q = 0; q < 8; ++q) { float v = p[(size_t)q * TT]; r[q] = __fmul_rn(v, v); }
        for (int i = 8; i < 128; i += 8) {
#pragma unroll
            for (int q = 0; q < 8; ++q) {
                float v = p[(size_t)(i + q) * TT];
                r[q] = __fadd_rn(r[q], __fmul_rn(v, v));
            }
        }
        h[hh] = __fadd_rn(__fadd_rn(__fadd_rn(r[0], r[1]), __fadd_rn(r[2], r[3])),
                          __fadd_rn(__fadd_rn(r[4], r[5]), __fadd_rn(r[6], r[7])));
    }
    znorm[m] = __fadd_rn(__fadd_rn(h[0], h[1]), __fadd_rn(h[2], h[3]));
}

// ---------------- enorm ------------------------------------------------------
__global__ void k_enorm(const float* __restrict__ emb, float* __restrict__ enorm) {
    int j = blockIdx.x * 256 + threadIdx.x;
    const float* base = emb + (size_t)j * EE;
    float h[4];
    for (int hh = 0; hh < 4; ++hh) {
        const float* p = base + hh * 128;
        float r[8];
#pragma unroll
        for (int q = 0; q < 8; ++q) { float v = p[q]; r[q] = __fmul_rn(v, v); }
        for (int i = 8; i < 128; i += 8) {
#pragma unroll
            for (int q = 0; q < 8; ++q) {
                float v = p[i + q];
                r[q] = __fadd_rn(r[q], __fmul_rn(v, v));
            }
        }
        h[hh] = __fadd_rn(__fadd_rn(__fadd_rn(r[0], r[1]), __fadd_rn(r[2], r[3])),
                          __fadd_rn(__fadd_rn(r[4], r[5]), __fadd_rn(r[6], r[7])));
    }
    enorm[j] = __fadd_rn(__fadd_rn(h[0], h[1]), __fadd_rn(h[2], h[3]));
}

// ---------------- prep: split emb into bf16 hi/lo ----------------------------
__global__ void k_prep_split(const float* __restrict__ emb,
                             ushort* __restrict__ eh, ushort* __restrict__ el) {
    int i = (blockIdx.x * 256 + threadIdx.x) * 4;   // 4.19M elements / 4
    float4 v = *(const float4*)&emb[i];
    ushort4 h4, l4;
    float f;
    h4.x = bf16_rtne(v.x, &f); l4.x = bf16_rtne(v.x - f, &f);
    h4.y = bf16_rtne(v.y, &f); l4.y = bf16_rtne(v.y - f, &f);
    h4.z = bf16_rtne(v.z, &f); l4.z = bf16_rtne(v.z - f, &f);
    h4.w = bf16_rtne(v.w, &f); l4.w = bf16_rtne(v.w - f, &f);
    *(ushort4*)&eh[i] = h4;
    *(ushort4*)&el[i] = l4;
}

// ---------------- main: 3-term bf16 MFMA distance GEMM + exact argmin --------
// Block: 64 z-rows x all 8192 codes. 8 waves, each wave: 64 codes x 64 rows.
// S^T tile via mfma_f32_32x32x16_bf16: D col=lane&31 (m), row=(reg&3)+8*(reg>>2)+4*(lane>>5) (j).
__global__ __launch_bounds__(512) void k_mainA(
    const float* __restrict__ z,
    const ushort* __restrict__ eh, const ushort* __restrict__ el,
    const float* __restrict__ znorm, const float* __restrict__ enorm,
    int* __restrict__ idx_out)
{
    __shared__ ushort ztH[64 * 512];   // z hi, row m: ushort idx = m*512 + (k ^ ((m&7)<<3))
    __shared__ ushort ztL[64 * 512];   // z lo
    __shared__ float  scD[64 * 16];
    __shared__ int    scJ[64 * 16];

    const int tid  = threadIdx.x;
    const int blk  = blockIdx.x;
    const int lane = tid & 63;
    const int wid  = tid >> 6;          // 0..7
    const int l31  = lane & 31;
    const int hh   = lane >> 5;         // k-half selector
    const int n    = blk >> 3;
    const int t0   = (blk & 7) * 64;
    const size_t zbase = (size_t)n * EE * TT + t0;

    // ---- stage z slice once: 64 rows x 512 k, split hi/lo, swizzled ----
    for (int i = tid; i < 64 * 512; i += 512) {
        int k  = i >> 6;
        int mr = i & 63;
        float v = z[zbase + (size_t)k * TT + mr];
        float fh;
        ushort hbits = bf16_rtne(v, &fh);
        float lo = v - fh;
        float fl_;
        ushort lbits = bf16_rtne(lo, &fl_);
        int off = mr * 512 + (k ^ ((mr & 7) << 3));
        ztH[off] = hbits;
        ztL[off] = lbits;
    }
    __syncthreads();

    // per-lane zn for its two m-columns
    float znv[2];
#pragma unroll
    for (int mt = 0; mt < 2; ++mt) znv[mt] = znorm[blk * 64 + mt * 32 + l31];

    float bd[2] = { 3.4028235e38f, 3.4028235e38f };
    int   bj[2] = { 0, 0 };

    for (int it = 0; it < NE / 512; ++it) {           // 16 iters, 512 codes each
        const int jb = it * 512 + wid * 64;           // this wave's 64-code window
        facc16 acc[2][2];
#pragma unroll
        for (int a = 0; a < 2; ++a)
#pragma unroll
            for (int b = 0; b < 2; ++b) acc[a][b] = (facc16)(0.0f);

#pragma unroll 2
        for (int ks = 0; ks < 32; ++ks) {             // K = 512 in steps of 16
            bfrag8 ah[2], al[2], bh[2], bl[2];
#pragma unroll
            for (int jt = 0; jt < 2; ++jt) {
                size_t ao = (size_t)(jb + jt * 32 + l31) * 512 + ks * 16 + 8 * hh;
                ah[jt] = *(const bfrag8*)&eh[ao];
                al[jt] = *(const bfrag8*)&el[ao];
            }
#pragma unroll
            for (int mt = 0; mt < 2; ++mt) {
                int mloc = mt * 32 + l31;
                int off = mloc * 512 + ((ks * 16 + 8 * hh) ^ ((mloc & 7) << 3));
                bh[mt] = *(const bfrag8*)&ztH[off];
                bl[mt] = *(const bfrag8*)&ztL[off];
            }
#pragma unroll
            for (int jt = 0; jt < 2; ++jt)
#pragma unroll
                for (int mt = 0; mt < 2; ++mt) {
                    acc[jt][mt] = __builtin_amdgcn_mfma_f32_32x32x16_bf16(
                        ah[jt], bh[mt], acc[jt][mt], 0, 0, 0);
                    acc[jt][mt] = __builtin_amdgcn_mfma_f32_32x32x16_bf16(
                        ah[jt], bl[mt], acc[jt][mt], 0, 0, 0);
                    acc[jt][mt] = __builtin_amdgcn_mfma_f32_32x32x16_bf16(
                        al[jt], bh[mt], acc[jt][mt], 0, 0, 0);
                }
        }

        // ---- fold: d = fl(fl(zn+en) - 2*dot), strict < with ascending j ----
#pragma unroll
        for (int jt = 0; jt < 2; ++jt) {
            float4 en4[4];
#pragma unroll
            for (int g = 0; g < 4; ++g)
                en4[g] = *(const float4*)&enorm[jb + jt * 32 + 8 * g + 4 * hh];
#pragma unroll
            for (int mt = 0; mt < 2; ++mt) {
                float zn_ = znv[mt];
#pragma unroll
                for (int g = 0; g < 4; ++g) {
#pragma unroll
                    for (int q = 0; q < 4; ++q) {
                        int r = g * 4 + q;   // acc row = q + 8g + 4hh
                        float enq = (q == 0) ? en4[g].x : (q == 1) ? en4[g].y
                                   : (q == 2) ? en4[g].z : en4[g].w;
                        float t = __fadd_rn(zn_, enq);
                        float d = fmaf(-2.0f, acc[jt][mt][r], t);
                        int j = jb + jt * 32 + 8 * g + 4 * hh + q;
                        if (d < bd[mt]) { bd[mt] = d; bj[mt] = j; }
                    }
                }
            }
        }
    }

    // ---- merge: per m, 16 partials (8 waves x 2 k-halves), tie -> lowest j ----
    __syncthreads();
#pragma unroll
    for (int mt = 0; mt < 2; ++mt) {
        int m = mt * 32 + l31;
        scD[m * 16 + wid * 2 + hh] = bd[mt];
        scJ[m * 16 + wid * 2 + hh] = bj[mt];
    }
    __syncthreads();
    if (tid < 64) {
        float d0 = scD[tid * 16];
        int   j0 = scJ[tid * 16];
        for (int s = 1; s < 16; ++s) {
            float dd = scD[tid * 16 + s];
            int   jj = scJ[tid * 16 + s];
            if (dd < d0 || (dd == d0 && jj < j0)) { d0 = dd; j0 = jj; }
        }
        idx_out[blk * 64 + tid] = j0;
    }
}

// ---------------- epilogue: z_q write + counts + loss partials ---------------
__global__ __launch_bounds__(512) void k_epilogue(
    const float* __restrict__ z, const float* __restrict__ emb,
    const int* __restrict__ idx,
    float* __restrict__ out_zq, int* __restrict__ counts,
    float* __restrict__ loss_part)
{
    __shared__ int bjs[64];
    __shared__ float lred[8];
    const int tid = threadIdx.x;
    const int blk = blockIdx.x;
    const int n   = blk >> 3;
    const int t0  = (blk & 7) * 64;
    const size_t zbase = (size_t)n * EE * TT + t0;

    if (tid < 64) {
        int j = idx[blk * 64 + tid];
        bjs[tid] = j;
        atomicAdd(&counts[j], 1);
    }
    __syncthreads();

    float lacc = 0.f;
    for (int i = tid; i < 64 * EE; i += 512) {
        int e  = i >> 6;
        int rr = i & 63;
        int j  = bjs[rr];
        float q  = emb[(size_t)j * EE + e];
        size_t zi = zbase + (size_t)e * TT + rr;
        float zf = z[zi];
        float diff = __fsub_rn(q, zf);
        out_zq[zi] = __fadd_rn(zf, diff);
        lacc = fmaf(diff, diff, lacc);
    }
#pragma unroll
    for (int off = 32; off; off >>= 1) lacc += __shfl_down(lacc, off);
    if ((tid & 63) == 0) lred[tid >> 6] = lacc;
    __syncthreads();
    if (tid == 0) {
        float s = ((lred[0] + lred[1]) + (lred[2] + lred[3]))
                + ((lred[4] + lred[5]) + (lred[6] + lred[7]));
        loss_part[blk] = s;
    }
}

// ---------------- final scalars ----------------------------------------------
__global__ void k_final(const int* __restrict__ counts,
                        const float* __restrict__ loss_part,
                        float* __restrict__ out)
{
    __shared__ float lw[4], pw[4];
    int tid = threadIdx.x;
    float l = loss_part[tid];
#pragma unroll
    for (int off = 32; off; off >>= 1) l += __shfl_down(l, off);
    if ((tid & 63) == 0) lw[tid >> 6] = l;
    float p = 0.f;
    for (int j = tid; j < NE; j += 256) {
        float e = (float)counts[j] * (1.0f / (float)MM);
        p += e * logf(e + 1e-10f);
    }
#pragma unroll
    for (int off = 32; off; off >>= 1) p += __shfl_down(p, off);
    if ((tid & 63) == 0) pw[tid >> 6] = p;
    __syncthreads();
    if (tid == 0) {
        float ls = (lw[0] + lw[1]) + (lw[2] + lw[3]);
        float m  = ls / (float)((size_t)MM * EE);
        out[(size_t)MM * EE] = m + 0.25f * m;
        float ps = (pw[0] + pw[1]) + (pw[2] + pw[3]);
        out[(size_t)MM * EE + 1] = expf(-ps);
    }
}

extern "C" void kernel_launch(void* const* d_in, const int* in_sizes, int n_in,
                              void* d_out, int out_size, void* d_ws, size_t ws_size,
                              hipStream_t stream) {
    const float* z   = (const float*)d_in[0];
    const float* emb = (const float*)d_in[1];
    float* out = (float*)d_out;

    // workspace layout
    float* znorm  = (float*)d_ws;                 // 16384 f32
    float* enorm  = znorm + MM;                   // 8192 f32
    int*   counts = (int*)(enorm + NE);           // 8192 i32
    float* parts  = (float*)(counts + NE);        // 256 f32
    int*   idx    = (int*)(parts + 256);          // 16384 i32
    ushort* eh    = (ushort*)(idx + MM);          // 8192*512 bf16 (8 MB)
    ushort* el    = eh + (size_t)NE * EE;         // 8 MB

    k_znorm<<<MM / 256, 256, 0, stream>>>(z, znorm);
    k_enorm<<<NE / 256, 256, 0, stream>>>(emb, enorm);
    k_prep_split<<<(NE * EE) / (256 * 4), 256, 0, stream>>>(emb, eh, el);
    hipMemsetAsync(counts, 0, NE * sizeof(int), stream);
    k_mainA<<<MM / 64, 512, 0, stream>>>(z, eh, el, znorm, enorm, idx);
    k_epilogue<<<MM / 64, 512, 0, stream>>>(z, emb, idx, out, counts, parts);
    k_final<<<1, 256, 0, stream>>>(counts, parts, out);
}